// Round 1
// 412.061 us; speedup vs baseline: 1.1172x; 1.1172x over previous
//
#include <hip/hip_runtime.h>
#include <hip/hip_bf16.h>
#include <math.h>

// Problem constants (B=16, N=1024, D=256, F=1024, H=8, hd=32)
#define Bq 16
#define Nq 1024
#define Dq 256
#define Fq 1024
#define Hq 8
#define HDq 32
#define Mq (Bq * Nq)          // 16384 rows
#define SCALE 0.0625f          // D^-0.5 = 1/16
#define LN_EPS 1e-5f

typedef __attribute__((ext_vector_type(8))) short short8;   // 8 bf16
typedef __attribute__((ext_vector_type(4))) float f32x4;

__device__ __forceinline__ float bf2f(unsigned short s) {
    unsigned u = ((unsigned)s) << 16;
    return __builtin_bit_cast(float, u);
}
__device__ __forceinline__ unsigned short f2bf(float f) {
    __hip_bfloat16 h = __float2bfloat16(f);
    return __builtin_bit_cast(unsigned short, h);
}

// async global->LDS, 16B per lane (lands at ldsbase + lane*16)
typedef __attribute__((address_space(3))) unsigned int lds_uint;
typedef const __attribute__((address_space(1))) unsigned int glb_uint;
__device__ __forceinline__ void async16(void* lds, const void* g) {
    __builtin_amdgcn_global_load_lds((glb_uint*)g, (lds_uint*)lds, 16, 0, 0);
}

__device__ __forceinline__ float gelu_tanh(float v) {
    const float c = 0.7978845608028654f;
    float u = c * (v + 0.044715f * v * v * v);
    return 0.5f * v * (1.0f + tanhf(u));
}

// ---------------------------------------------------------------------------
// Kernel 0: convert the 6 weight matrices to bf16 (Wq,Wk,Wv rows 0..767 of W16)
// ---------------------------------------------------------------------------
__global__ __launch_bounds__(256) void cvt_weights(
    const float* __restrict__ Wq, const float* __restrict__ Wk,
    const float* __restrict__ Wv, const float* __restrict__ Wo,
    const float* __restrict__ W1, const float* __restrict__ W2,
    unsigned short* __restrict__ dst)
{
    const int blk = blockIdx.x;
    int seg, local;
    if (blk < 256)      { seg = blk >> 6; local = blk & 63; }
    else if (blk < 512) { seg = 4; local = blk - 256; }
    else                { seg = 5; local = blk - 512; }
    const float* srcs[6] = {Wq, Wk, Wv, Wo, W1, W2};
    const size_t dsto[6] = {0, 65536, 131072, 196608, 262144, 524288};
    const float* src = srcs[seg] + (size_t)local * 1024;
    unsigned short* d = dst + dsto[seg] + (size_t)local * 1024;
    const int t4 = threadIdx.x * 4;
    float4 v = *(const float4*)(src + t4);
    uint2 o;
    o.x = (unsigned)f2bf(v.x) | ((unsigned)f2bf(v.y) << 16);
    o.y = (unsigned)f2bf(v.z) | ((unsigned)f2bf(v.w) << 16);
    *(uint2*)(d + t4) = o;
}

// ---------------------------------------------------------------------------
// Kernel 1: fused double LayerNorm -> bf16 outputs (shared mean/rstd)
// ---------------------------------------------------------------------------
__global__ __launch_bounds__(256) void ln2_kernel(
    const float* __restrict__ x,
    const float* __restrict__ g1, const float* __restrict__ bb1,
    const float* __restrict__ g2, const float* __restrict__ bb2,
    unsigned short* __restrict__ att_in, unsigned short* __restrict__ ffn_in)
{
    const int row = blockIdx.x;
    const int t = threadIdx.x;
    const size_t base = (size_t)row * Dq;
    float v = x[base + t];

    float s = v, sq = v * v;
    #pragma unroll
    for (int off = 32; off > 0; off >>= 1) {
        s  += __shfl_down(s, off);
        sq += __shfl_down(sq, off);
    }
    __shared__ float ssum[4], ssq[4];
    __shared__ float mu_s, rstd_s;
    const int lane = t & 63, wid = t >> 6;
    if (lane == 0) { ssum[wid] = s; ssq[wid] = sq; }
    __syncthreads();
    if (t == 0) {
        float S = ssum[0] + ssum[1] + ssum[2] + ssum[3];
        float Q = ssq[0] + ssq[1] + ssq[2] + ssq[3];
        float mu = S * (1.0f / Dq);
        float var = Q * (1.0f / Dq) - mu * mu;
        mu_s = mu;
        rstd_s = rsqrtf(var + LN_EPS);
    }
    __syncthreads();
    const float nx = (v - mu_s) * rstd_s;
    att_in[base + t] = f2bf(nx * g1[t] + bb1[t]);
    ffn_in[base + t] = f2bf(nx * g2[t] + bb2[t]);
}

// ---------------------------------------------------------------------------
// Kernel 2: MFMA NT GEMM  C[M,Nc] = A[M,K] * W[Nc,K]^T  (bf16 in, fp32 acc)
// 128x128 tile, BK=32, operand-swapped (W = A-operand) for vector epilogue.
// mode 0: fp32 out (+bias,+gelu,+add)   [Wo, FFN2]
// mode 1: bf16 flat out (+bias,+gelu)   [FFN1]
// mode 2: merged QKV (Nc=768): Q scaled+head-major, K head-major, V transposed
// ---------------------------------------------------------------------------
#define TM 128
#define TN 128
#define TK 32

__global__ __launch_bounds__(256) void gemm_mfma(
    const unsigned short* __restrict__ A, const unsigned short* __restrict__ W,
    const float* __restrict__ bias, const float* __restrict__ add,
    float* __restrict__ outF, unsigned short* __restrict__ outBF,
    unsigned short* __restrict__ Qb, unsigned short* __restrict__ Kb,
    unsigned short* __restrict__ Vt,
    int M, int Nc, int K, int mode, int apply_gelu)
{
    __shared__ unsigned short As[TM * TK];   // 8 KB
    __shared__ unsigned short Bs[TN * TK];   // 8 KB
    const int t = threadIdx.x;
    const int w = t >> 6, lane = t & 63;
    const int col = lane & 15, quad = lane >> 4;
    const int wr = w >> 1, wc = w & 1;
    const int row0 = blockIdx.y * TM;
    const int col0 = blockIdx.x * TN;

    f32x4 acc[4][4] = {};

    for (int k0 = 0; k0 < K; k0 += TK) {
        #pragma unroll
        for (int j = 0; j < 2; j++) {
            const int c = w * 128 + j * 64 + lane;   // chunk 0..511 (16B each)
            const int r = c >> 2, seg = c & 3;
            async16(&As[(size_t)(w * 128 + j * 64) * 8],
                    A + (size_t)(row0 + r) * K + k0 + seg * 8);
            async16(&Bs[(size_t)(w * 128 + j * 64) * 8],
                    W + (size_t)(col0 + r) * K + k0 + seg * 8);
        }
        __syncthreads();   // drains vmcnt (global_load_lds) + barrier
        short8 wf[4], af[4];
        #pragma unroll
        for (int i = 0; i < 4; i++)
            wf[i] = *(const short8*)&Bs[(wc * 64 + i * 16 + col) * TK + quad * 8];
        #pragma unroll
        for (int j = 0; j < 4; j++)
            af[j] = *(const short8*)&As[(wr * 64 + j * 16 + col) * TK + quad * 8];
        // D[c][r]: A-operand = W rows (c), B-operand = A rows (r)
        #pragma unroll
        for (int i = 0; i < 4; i++)
            #pragma unroll
            for (int j = 0; j < 4; j++)
                acc[i][j] = __builtin_amdgcn_mfma_f32_16x16x32_bf16(wf[i], af[j], acc[i][j], 0, 0, 0);
        __syncthreads();
    }

    // epilogue: lane owns cols c0..c0+3 (consecutive), output row r
    #pragma unroll
    for (int i = 0; i < 4; i++) {
        #pragma unroll
        for (int j = 0; j < 4; j++) {
            const int c0 = col0 + wc * 64 + i * 16 + quad * 4;
            const int r  = row0 + wr * 64 + j * 16 + col;
            float4 v = make_float4(acc[i][j][0], acc[i][j][1], acc[i][j][2], acc[i][j][3]);
            if (mode == 2 && c0 < 256) { v.x *= SCALE; v.y *= SCALE; v.z *= SCALE; v.w *= SCALE; }
            if (bias) {
                float4 bb = *(const float4*)&bias[c0];
                v.x += bb.x; v.y += bb.y; v.z += bb.z; v.w += bb.w;
            }
            if (apply_gelu) {
                v.x = gelu_tanh(v.x); v.y = gelu_tanh(v.y);
                v.z = gelu_tanh(v.z); v.w = gelu_tanh(v.w);
            }
            if (add) {
                float4 aa = *(const float4*)&add[(size_t)r * Nc + c0];
                v.x += aa.x; v.y += aa.y; v.z += aa.z; v.w += aa.w;
            }
            if (mode == 0) {
                *(float4*)&outF[(size_t)r * Nc + c0] = v;
            } else if (mode == 1) {
                uint2 o;
                o.x = (unsigned)f2bf(v.x) | ((unsigned)f2bf(v.y) << 16);
                o.y = (unsigned)f2bf(v.z) | ((unsigned)f2bf(v.w) << 16);
                *(uint2*)&outBF[(size_t)r * Nc + c0] = o;
            } else {
                const int b = r >> 10, n = r & 1023;
                if (c0 < 512) {
                    // Q (c0<256, pre-scaled) or K: head-major [B,H,N,32]
                    const int cq = c0 & 255;
                    const int h = cq >> 5, d0 = cq & 31;
                    unsigned short* dst = (c0 < 256 ? Qb : Kb);
                    uint2 o;
                    o.x = (unsigned)f2bf(v.x) | ((unsigned)f2bf(v.y) << 16);
                    o.y = (unsigned)f2bf(v.z) | ((unsigned)f2bf(v.w) << 16);
                    *(uint2*)&dst[(((size_t)(b * Hq + h) << 10) + n) * HDq + d0] = o;
                } else {
                    // V transposed: Vt[B,H,32,N]
                    const int cv = c0 - 512;
                    const int h = cv >> 5, d0 = cv & 31;
                    unsigned short* dst = Vt + (((size_t)(b * Hq + h) * HDq + d0) << 10) + n;
                    dst[0]      = f2bf(v.x);
                    dst[1024]   = f2bf(v.y);
                    dst[2048]   = f2bf(v.z);
                    dst[3072]   = f2bf(v.w);
                }
            }
        }
    }
}

// ---------------------------------------------------------------------------
// Kernel 3: MFMA attention, wave-autonomous flash-style.
// Block = (b, 16 q-rows), 512 threads = 8 waves, wave w == head w.
// Bias slice bf16(sp+ed) staged in LDS ONCE (HBM bias bytes fetched exactly
// once), then ONE barrier; after that zero cross-wave interaction:
//   per wave, per 128-key tile: 8x QK^T MFMA -> +bias, exp -> 4KB swizzled
//   per-wave S-tile -> 8x PV MFMA. Row sums live in registers (the rsum[i]
//   row mapping quad*4+i equals the PV C-layout row mapping), reduced with
//   shfl_xor(width 16) at the end -> no LDS reduction, no inv_row barrier.
// LDS 65.7KB -> 2 blocks/CU = 16 waves/CU (vs 8 before).
// S-tile XOR swizzle (short idx ^= (row&7)<<3): conflict-free b128 PV reads.
// Bias stride 1028 shorts: row step = 2 dwords mod 32 -> conflict-free u16.
// ---------------------------------------------------------------------------
#define BSTR 1028   // bias16 row stride in shorts (1024 + 4 pad)

__global__ __launch_bounds__(512, 4) void attn_mfma(
    const unsigned short* __restrict__ Qbf, const unsigned short* __restrict__ Kbf,
    const unsigned short* __restrict__ Vt, const float* __restrict__ sp,
    const float* __restrict__ ed, unsigned short* __restrict__ O16)
{
    const int b = blockIdx.y;
    const int n0 = blockIdx.x * 16;
    const int t = threadIdx.x;
    const int h = t >> 6;            // wave index == head
    const int lane = t & 63;
    const int col = lane & 15;
    const int quad = lane >> 4;

    __shared__ unsigned short bias16[16 * BSTR];   // 32.9 KB, head-invariant
    __shared__ unsigned short S16[8][16 * 128];    // 32 KB, 4KB per wave

    // ---- stage bf16(sp+ed) for our 16 rows (read fp32 exactly once)
    {
        const float* spb = sp + ((size_t)b * Nq + n0) * Nq;
        const float* edb = ed + ((size_t)b * Nq + n0) * Nq;
        for (int i = t; i < 4096; i += 512) {          // 4096 float4-groups
            const int r = i >> 8;                      // row 0..15
            const int c4 = i & 255;                    // float4 index in row
            float4 a = *(const float4*)(spb + (size_t)r * Nq + c4 * 4);
            float4 e = *(const float4*)(edb + (size_t)r * Nq + c4 * 4);
            uint2 o;
            o.x = (unsigned)f2bf(a.x + e.x) | ((unsigned)f2bf(a.y + e.y) << 16);
            o.y = (unsigned)f2bf(a.z + e.z) | ((unsigned)f2bf(a.w + e.w) << 16);
            *(uint2*)&bias16[r * BSTR + c4 * 4] = o;
        }
    }
    __syncthreads();   // the ONLY barrier

    const size_t hb = (size_t)b * Hq + h;
    const unsigned short* Qh = Qbf + hb * (Nq * HDq);
    const unsigned short* Kh = Kbf + hb * (Nq * HDq);
    const unsigned short* Vh = Vt  + hb * (HDq * Nq);
    unsigned short* Sw = &S16[h][0];

    // A-frag: Q rows n0..n0+15 (pre-scaled by 1/16 in gemm epilogue)
    const short8 aq = *(const short8*)(Qh + (size_t)(n0 + col) * HDq + quad * 8);

    f32x4 o0 = {0.f, 0.f, 0.f, 0.f}, o1 = {0.f, 0.f, 0.f, 0.f};
    float rsum[4] = {0.f, 0.f, 0.f, 0.f};

    for (int tt = 0; tt < 8; tt++) {                   // 128-key flash tiles
        const int k0 = tt * 128;
        // ---- QK^T + bias + exp -> per-wave swizzled S-tile
        #pragma unroll
        for (int m = 0; m < 8; m++) {
            const int m0 = k0 + m * 16;
            short8 bk = *(const short8*)(Kh + (size_t)(m0 + col) * HDq + quad * 8);
            f32x4 cc = {0.f, 0.f, 0.f, 0.f};
            cc = __builtin_amdgcn_mfma_f32_16x16x32_bf16(aq, bk, cc, 0, 0, 0);
            #pragma unroll
            for (int i = 0; i < 4; i++) {
                const int r = quad * 4 + i;
                float s = cc[i] + bf2f(bias16[r * BSTR + m0 + col]);
                float e = __expf(s);
                rsum[i] += e;
                const int sidx = (r * 128 + m * 16 + col) ^ ((r & 7) << 3);
                Sw[sidx] = f2bf(e);
            }
        }
        // ---- PV: S-tile (16x128) @ V^T-rows, accumulate (same-wave LDS RAW:
        //      compiler inserts lgkmcnt waits; no barrier needed)
        #pragma unroll
        for (int c = 0; c < 4; c++) {
            const int ridx = (col * 128 + c * 32 + quad * 8) ^ ((col & 7) << 3);
            short8 ap  = *(const short8*)&Sw[ridx];
            short8 bv0 = *(const short8*)(Vh + (size_t)col * Nq + k0 + c * 32 + quad * 8);
            short8 bv1 = *(const short8*)(Vh + (size_t)(col + 16) * Nq + k0 + c * 32 + quad * 8);
            o0 = __builtin_amdgcn_mfma_f32_16x16x32_bf16(ap, bv0, o0, 0, 0, 0);
            o1 = __builtin_amdgcn_mfma_f32_16x16x32_bf16(ap, bv1, o1, 0, 0, 0);
        }
    }

    // ---- in-register row-sum reduce across the 16 col-lanes of each quad
    #pragma unroll
    for (int off = 1; off < 16; off <<= 1) {
        #pragma unroll
        for (int i = 0; i < 4; i++) rsum[i] += __shfl_xor(rsum[i], off, 16);
    }

    // ---- normalize + store: lane owns rows quad*4+i, cols col / col+16
    unsigned short* op = O16 + ((size_t)b * Nq + n0) * Dq + h * HDq;
    #pragma unroll
    for (int i = 0; i < 4; i++) {
        const float inv = 1.0f / rsum[i];
        const int q = quad * 4 + i;
        op[(size_t)q * Dq + col]      = f2bf(o0[i] * inv);
        op[(size_t)q * Dq + col + 16] = f2bf(o1[i] * inv);
    }
}

// ---------------------------------------------------------------------------
// Kernel 4: pad_mask2 — zero rows of out where att_output has any exact 0
// ---------------------------------------------------------------------------
__global__ __launch_bounds__(256) void pad2_kernel(
    const float* __restrict__ AO, float* __restrict__ out)
{
    const int row = blockIdx.x;
    const int t = threadIdx.x;
    const float v = AO[(size_t)row * Dq + t];
    unsigned long long m = __ballot(v == 0.0f);
    __shared__ unsigned long long w[4];
    if ((t & 63) == 0) w[t >> 6] = m;
    __syncthreads();
    if ((w[0] | w[1] | w[2] | w[3]) != 0ULL)
        out[(size_t)row * Dq + t] = 0.0f;
}

// ---------------------------------------------------------------------------
extern "C" void kernel_launch(void* const* d_in, const int* in_sizes, int n_in,
                              void* d_out, int out_size, void* d_ws, size_t ws_size,
                              hipStream_t stream)
{
    const float* x      = (const float*)d_in[0];
    const float* sp     = (const float*)d_in[1];
    const float* ed     = (const float*)d_in[2];
    const float* gamma1 = (const float*)d_in[3];
    const float* beta1  = (const float*)d_in[4];
    const float* gamma2 = (const float*)d_in[5];
    const float* beta2  = (const float*)d_in[6];
    const float* Wq     = (const float*)d_in[7];
    const float* Wk     = (const float*)d_in[8];
    const float* Wv     = (const float*)d_in[9];
    const float* Wo     = (const float*)d_in[10];
    const float* W1     = (const float*)d_in[11];
    const float* b1     = (const float*)d_in[12];
    const float* W2     = (const float*)d_in[13];
    const float* b2     = (const float*)d_in[14];
    float* out = (float*)d_out;

    // workspace layout (in shorts)
    unsigned short* s = (unsigned short*)d_ws;
    const size_t MD = (size_t)Mq * Dq;                  // 4.19M elements
    unsigned short* att_in16 = s;                        // [M,D] bf16; reused as O16
    unsigned short* ffn_in16 = s + MD;                   // [M,D] bf16
    unsigned short* Qbf      = s + 2 * MD;               // [B,H,N,32] bf16
    unsigned short* Kbf      = s + 3 * MD;               // [B,H,N,32] bf16
    unsigned short* Vtb      = s + 4 * MD;               // [B,H,32,N] bf16 (transposed)
    unsigned short* W16      = s + 5 * MD;               // 786432 shorts
    unsigned short* h16      = s + 5 * MD + 786432;      // [M,F] bf16 (33.5 MB)
    unsigned short* O16      = att_in16;                 // attn out (att_in dead)
    float*          AO       = (float*)Qbf;              // [M,D] fp32 (Q/K dead)

    unsigned short* Wo16 = W16 + 196608;
    unsigned short* W116 = W16 + 262144;
    unsigned short* W216 = W16 + 524288;

    // 0) weights -> bf16 (Wq/Wk/Wv contiguous as rows 0..767 for merged QKV)
    cvt_weights<<<768, 256, 0, stream>>>(Wq, Wk, Wv, Wo, W1, W2, W16);

    // 1) both layernorms -> bf16
    ln2_kernel<<<Mq, 256, 0, stream>>>(x, gamma1, beta1, gamma2, beta2, att_in16, ffn_in16);

    // 2) merged QKV projection (Q scaled + head-major, K head-major, V transposed)
    dim3 gQKV(768 / TN, Mq / TM);   // (6, 128)
    gemm_mfma<<<gQKV, 256, 0, stream>>>(att_in16, W16, nullptr, nullptr, nullptr, nullptr,
                                        Qbf, Kbf, Vtb, Mq, 768, Dq, 2, 0);

    // 3) MFMA attention: block=(qt,b), 8 waves = 8 heads -> O16 (bf16 [B,N,D])
    attn_mfma<<<dim3(Nq / 16, Bq), 512, 0, stream>>>(Qbf, Kbf, Vtb, sp, ed, O16);

    // 4) output projection + residual: AO = O @ Wo^T + x   (fp32)
    dim3 gP(Dq / TN, Mq / TM);
    gemm_mfma<<<gP, 256, 0, stream>>>(O16, Wo16, nullptr, x, AO, nullptr,
                                      nullptr, nullptr, nullptr, Mq, Dq, Dq, 0, 0);

    // 5) FFN1: h16 = bf16(gelu(ffn_in @ W1^T + b1))
    dim3 gF1(Fq / TN, Mq / TM);
    gemm_mfma<<<gF1, 256, 0, stream>>>(ffn_in16, W116, b1, nullptr, nullptr, h16,
                                       nullptr, nullptr, nullptr, Mq, Fq, Dq, 1, 1);

    // 6) FFN2: out = h @ W2^T + b2 + AO
    gemm_mfma<<<gP, 256, 0, stream>>>(h16, W216, b2, AO, out, nullptr,
                                      nullptr, nullptr, nullptr, Mq, Dq, Fq, 0, 0);

    // 7) pad_mask2 row zeroing
    pad2_kernel<<<Mq, 256, 0, stream>>>(AO, out);
}